// Round 26
// baseline (591.350 us; speedup 1.0000x reference)
//
#include <hip/hip_runtime.h>

typedef float f32x4 __attribute__((ext_vector_type(4)));
typedef float f32x2 __attribute__((ext_vector_type(2)));
typedef __bf16 bf16x8 __attribute__((ext_vector_type(8)));
typedef __bf16 bf16x4 __attribute__((ext_vector_type(4)));

__device__ __forceinline__ void gll16(const void* g, void* l) {
  __builtin_amdgcn_global_load_lds(
      (const __attribute__((address_space(1))) uint32_t*)g,
      (__attribute__((address_space(3))) uint32_t*)l, 16, 0, 0);
}

// ---------------------------------------------------------------------------
// GEMM 256x256 tile, 16 waves (4M x 4N, per-wave 64x64, acc[4][4]):
// C = A[Mx512]@B[512xN]+bias. BK=64. Same proven dbuf schedule as R21
// (stage(t+1) before compute(t), plain __syncthreads) but 4 waves/SIMD
// instead of 2 -> intra-phase wave overlap (m114) hides ds_read + stage
// latency under other waves' MFMA. Same 0-conflict XOR chunk swizzle
// (chunk ^= row&7); XCD-chunked remap; swapped-mfma epilogue, bf16x4 stores.
// ---------------------------------------------------------------------------
__global__ __launch_bounds__(1024, 1) void gemm256(
    const __bf16* __restrict__ A, const __bf16* __restrict__ BT,
    const float* __restrict__ bias, __bf16* __restrict__ C, int N, int gx)
{
  __shared__ __bf16 As[2][16384];   // 2 x 256x64 (32 KB each)
  __shared__ __bf16 Bs[2][16384];   // total 128 KB
  const int tid = threadIdx.x;       // 0..1023
  const int wave = tid >> 6, lane = tid & 63;
  const int wr = (wave >> 2) * 64;   // 0,64,128,192
  const int wc = (wave & 3) * 64;    // 0,64,128,192
  const int l15 = lane & 15, l4 = lane >> 4;

  // XCD-chunked bijective remap (gridDim.x % 8 == 0)
  int lin = blockIdx.x;
  int olin = (lin & 7) * ((int)gridDim.x >> 3) + (lin >> 3);
  int bn = olin % gx, bm = olin / gx;
  const long arow0 = (long)bm * 256;
  const long brow0 = (long)bn * 256;

  // staging: sweep s covers rows s*128..s*128+127; LDS byte = s*16384 + tid*16
  //   row = s*128 + (tid>>3), chunk = tid&7; row&7 == (tid>>3)&7
  const int srow = tid >> 3;         // 0..127
  const int sgc = ((tid & 7) ^ (srow & 7)) * 8;   // inverse-swizzled global chunk

  f32x4 acc[4][4] = {};

  auto stage = [&](int p, int kt) {
    #pragma unroll
    for (int s = 0; s < 2; s++) {
      int row = srow + s * 128;      // row&7 == srow&7 (s*128 % 8 == 0)
      gll16(A  + (arow0 + row) * 512 + kt + sgc, (char*)As[p] + s * 16384 + tid * 16);
      gll16(BT + (brow0 + row) * 512 + kt + sgc, (char*)Bs[p] + s * 16384 + tid * 16);
    }
  };

  stage(0, 0);
  __syncthreads();                  // drain prologue stage

  for (int t = 0; t < 8; t++) {
    int cur = t & 1;
    if (t < 7) stage(cur ^ 1, (t + 1) * 64);   // prefetch next K-tile (overlaps compute)
    #pragma unroll
    for (int kk = 0; kk < 2; kk++) {
      bf16x8 af[4], bfr[4];
      #pragma unroll
      for (int m = 0; m < 4; m++) {
        int row = wr + m * 16 + l15;
        int cp = ((kk * 4 + l4) ^ (row & 7)) * 8;
        af[m] = *(const bf16x8*)&As[cur][row * 64 + cp];
      }
      #pragma unroll
      for (int n = 0; n < 4; n++) {
        int row = wc + n * 16 + l15;
        int cp = ((kk * 4 + l4) ^ (row & 7)) * 8;
        bfr[n] = *(const bf16x8*)&Bs[cur][row * 64 + cp];
      }
      // swapped operands: lane holds C[row = wr+m*16+l15][col = wc+n*16+l4*4+k]
      #pragma unroll
      for (int m = 0; m < 4; m++)
        #pragma unroll
        for (int n = 0; n < 4; n++)
          acc[m][n] = __builtin_amdgcn_mfma_f32_16x16x32_bf16(bfr[n], af[m], acc[m][n], 0, 0, 0);
    }
    if (t < 7) __syncthreads();     // drains landed prefetch + WAR hazard
  }

  // epilogue: direct bf16x4 stores (4 consecutive cols per lane)
  #pragma unroll
  for (int m = 0; m < 4; m++) {
    long row = arow0 + wr + m * 16 + l15;
    __bf16* crow = C + row * (long)N + brow0;
    #pragma unroll
    for (int n = 0; n < 4; n++) {
      f32x4 bv = *(const f32x4*)(bias + brow0 + wc + n * 16 + l4 * 4);
      bf16x4 o;
      #pragma unroll
      for (int k = 0; k < 4; k++) o[k] = (__bf16)(acc[m][n][k] + bv[k]);
      *(bf16x4*)(crow + wc + n * 16 + l4 * 4) = o;
    }
  }
}

// ---------------------------------------------------------------------------
// Window attention v3: 2x2 windows, 8 heads, hd=64.
// 4 threads per (window, head) -- one per query token; full 128B rows
// consumed back-to-back; group-of-4 lanes share K/V addresses (L1 broadcast).
// ---------------------------------------------------------------------------
__global__ __launch_bounds__(256) void attn4(
    const __bf16* __restrict__ qkv, __bf16* __restrict__ o,
    int nwin, int wg, int Wimg, int wpb, int bst)
{
  int tid = blockIdx.x * 256 + threadIdx.x;
  int m = tid & 3;
  int head = (tid >> 2) & 7;
  int win = tid >> 5;
  if (win >= nwin) return;
  int b = win / wpb, wrm = win % wpb;
  int i = wrm / wg, j = wrm % wg;
  int t0 = b * bst + 2 * i * Wimg + 2 * j;
  int tn[4] = { t0, t0 + 1, t0 + Wimg, t0 + Wimg + 1 };
  int trow = tn[m];
  const int co = head * 64;

  float qf[64];
  #pragma unroll
  for (int c = 0; c < 8; c++) {
    bf16x8 v = *(const bf16x8*)(qkv + (long)trow * 1536 + co + c * 8);
    #pragma unroll
    for (int e = 0; e < 8; e++) qf[c * 8 + e] = (float)v[e];
  }

  float s[4];
  #pragma unroll
  for (int n = 0; n < 4; n++) {
    float acc = 0.f;
    #pragma unroll
    for (int c = 0; c < 8; c++) {
      bf16x8 kv = *(const bf16x8*)(qkv + (long)tn[n] * 1536 + 512 + co + c * 8);
      #pragma unroll
      for (int e = 0; e < 8; e++) acc += qf[c * 8 + e] * (float)kv[e];
    }
    s[n] = acc * 0.125f;
  }

  float mx = fmaxf(fmaxf(s[0], s[1]), fmaxf(s[2], s[3]));
  float e0 = __expf(s[0] - mx), e1 = __expf(s[1] - mx),
        e2 = __expf(s[2] - mx), e3 = __expf(s[3] - mx);
  float inv = 1.f / (e0 + e1 + e2 + e3);
  float w4[4] = { e0 * inv, e1 * inv, e2 * inv, e3 * inv };

  float of[64] = {};
  #pragma unroll
  for (int n = 0; n < 4; n++) {
    float wn = w4[n];
    #pragma unroll
    for (int c = 0; c < 8; c++) {
      bf16x8 vv = *(const bf16x8*)(qkv + (long)tn[n] * 1536 + 1024 + co + c * 8);
      #pragma unroll
      for (int e = 0; e < 8; e++) of[c * 8 + e] += wn * (float)vv[e];
    }
  }

  #pragma unroll
  for (int c = 0; c < 8; c++) {
    bf16x8 ov;
    #pragma unroll
    for (int e = 0; e < 8; e++) ov[e] = (__bf16)of[c * 8 + e];
    *(bf16x8*)(o + (long)trow * 512 + co + c * 8) = ov;
  }
}

// Transpose + fp32->bf16: out[N][K] = (bf16) in[K][N]
__global__ __launch_bounds__(256) void transpose_f32_bf16(
    const float* __restrict__ in, __bf16* __restrict__ out, int K, int N)
{
  __shared__ float t[64][65];
  int n0 = blockIdx.x * 64, k0 = blockIdx.y * 64;
  int tid = threadIdx.x;
  int nl4 = (tid & 15) * 4, kl = tid >> 4;
  #pragma unroll
  for (int p = 0; p < 4; p++) {
    int kk = kl + p * 16;
    f32x4 v = *(const f32x4*)(in + (long)(k0 + kk) * N + n0 + nl4);
    t[kk][nl4 + 0] = v.x; t[kk][nl4 + 1] = v.y; t[kk][nl4 + 2] = v.z; t[kk][nl4 + 3] = v.w;
  }
  __syncthreads();
  int ks = tid & 63, wv = tid >> 6;
  #pragma unroll
  for (int p = 0; p < 16; p++) {
    int nn = wv * 16 + p;
    out[(long)(n0 + nn) * K + k0 + ks] = (__bf16)t[ks][nn];
  }
}

// Fused: Xbf = bf16(x) (flat) AND P = AvgPool2d(2) of x viewed (B,C,128,128).
__global__ __launch_bounds__(256) void convpool(const float* __restrict__ x,
    __bf16* __restrict__ Xbf, __bf16* __restrict__ P)
{
  int t = blockIdx.x * 256 + threadIdx.x;   // 2,097,152 threads
  int j8 = (t & 15) * 8;
  int i2 = (t >> 4) & 63;
  long bc = t >> 10;
  const float* r0 = x + bc * 16384 + (2 * i2) * 128 + j8;
  f32x4 a0 = *(const f32x4*)r0,         a1 = *(const f32x4*)(r0 + 4);
  f32x4 b0 = *(const f32x4*)(r0 + 128), b1 = *(const f32x4*)(r0 + 132);
  bf16x8 xa, xb;
  xa[0] = (__bf16)a0.x; xa[1] = (__bf16)a0.y; xa[2] = (__bf16)a0.z; xa[3] = (__bf16)a0.w;
  xa[4] = (__bf16)a1.x; xa[5] = (__bf16)a1.y; xa[6] = (__bf16)a1.z; xa[7] = (__bf16)a1.w;
  xb[0] = (__bf16)b0.x; xb[1] = (__bf16)b0.y; xb[2] = (__bf16)b0.z; xb[3] = (__bf16)b0.w;
  xb[4] = (__bf16)b1.x; xb[5] = (__bf16)b1.y; xb[6] = (__bf16)b1.z; xb[7] = (__bf16)b1.w;
  *(bf16x8*)(Xbf + bc * 16384 + (2 * i2) * 128 + j8) = xa;
  *(bf16x8*)(Xbf + bc * 16384 + (2 * i2) * 128 + 128 + j8) = xb;
  bf16x4 p;
  p[0] = (__bf16)((a0.x + a0.y + b0.x + b0.y) * 0.25f);
  p[1] = (__bf16)((a0.z + a0.w + b0.z + b0.w) * 0.25f);
  p[2] = (__bf16)((a1.x + a1.y + b1.x + b1.y) * 0.25f);
  p[3] = (__bf16)((a1.z + a1.w + b1.z + b1.w) * 0.25f);
  *(bf16x4*)(P + bc * 4096 + i2 * 64 + (t & 15) * 4) = p;
}

// ---------------------------------------------------------------------------
// final_v6: one block per (yy, b) stages Ol + stencil ONCE, then loops over
// all 8 c-tiles (xx). Ol traffic /8, stencil /8, per-block work x8.
// LDS: t[64][65] overlays dead lbuf; 49.4KB -> 3 blocks/CU.
// ---------------------------------------------------------------------------
__global__ __launch_bounds__(256) void final_v6(
    const __bf16* __restrict__ G, const __bf16* __restrict__ Ol, float* __restrict__ out)
{
  __shared__ float smem[12352];                 // 49408 B
  float (*t)[65] = (float(*)[65])smem;          // [0, 16640)
  float* Sl = smem + 4160;                      // [16640, 49408): 8192 floats
  __bf16* lbuf = (__bf16*)smem;                 // [0, 16384): 8192 bf16

  int yy = blockIdx.x;             // 0..255 : p-tile / S-pair index
  int b  = blockIdx.y;
  int p0 = yy * 64;
  int tid = threadIdx.x;

  // phase 1: stage the block's two O_l channels (raw-reshape view)
  {
    const __bf16* src = Ol + ((long)b * 512 + (long)yy * 2) * 4096;
    #pragma unroll
    for (int i = 0; i < 4; i++)
      *(bf16x8*)&lbuf[i * 2048 + tid * 8] = *(const bf16x8*)(src + i * 2048 + tid * 8);
  }
  __syncthreads();

  // phase 2: stencil -> Sl (reflect pad baked in)
  #pragma unroll
  for (int kq = 0; kq < 32; kq++) {
    int s = tid + kq * 256;
    int j = s & 63, i = (s >> 6) & 63, lc = s >> 12;
    const __bf16* base = lbuf + lc * 4096;
    int im1 = (i == 0) ? 1 : i - 1;
    int jp1 = (j == 63) ? 62 : j + 1;
    Sl[s] = 0.5f * (float)base[im1 * 64 + j] + (float)base[i * 64 + j]
          + 0.5f * (float)base[i * 64 + jp1];
  }
  __syncthreads();   // lbuf dead from here; t overlays it

  int cl4 = (tid & 15) * 4, pl = tid >> 4;
  int l15b = tid & 15, hi = (tid >> 4) & 3, wv = tid >> 6;

  for (int xx = 0; xx < 8; xx++) {
    int c0 = xx * 64;
    const __bf16* Gb = G + ((long)b * 16384 + p0) * 512 + c0;
    #pragma unroll
    for (int q2 = 0; q2 < 4; q2++) {
      int pp = pl + q2 * 16;
      bf16x4 g = *(const bf16x4*)(Gb + (long)pp * 512 + cl4);
      int q = (p0 + pp) * 512 + c0 + cl4;            // quad-aligned
      int lc = (q >> 14) & 1;
      int rr = q & 16383, hh = rr >> 7, ww0 = rr & 127;
      const float* sb = Sl + lc * 4096;
      int i0, i1; float wi0, wi1;
      if (hh & 1) { i0 = hh >> 1; i1 = (i0 < 63) ? i0 + 1 : 63; wi0 = 0.75f; wi1 = 0.25f; }
      else        { i1 = hh >> 1; i0 = (i1 > 0) ? i1 - 1 : 0;   wi0 = 0.25f; wi1 = 0.75f; }
      int kc = ww0 >> 1;
      int cm1 = (kc > 0) ? kc - 1 : 0;
      int cp2 = (kc < 62) ? kc + 2 : 63;
      const float* r0p = sb + i0 * 64;
      const float* r1p = sb + i1 * 64;
      float a0 = r0p[cm1], a1 = r0p[kc], a2 = r0p[kc + 1], a3 = r0p[cp2];
      float b0 = r1p[cm1], b1 = r1p[kc], b2 = r1p[kc + 1], b3 = r1p[cp2];
      float h0 = wi0 * (0.25f * a0 + 0.75f * a1) + wi1 * (0.25f * b0 + 0.75f * b1);
      float h1 = wi0 * (0.75f * a1 + 0.25f * a2) + wi1 * (0.75f * b1 + 0.25f * b2);
      float h2 = wi0 * (0.25f * a1 + 0.75f * a2) + wi1 * (0.25f * b1 + 0.75f * b2);
      float h3 = wi0 * (0.75f * a2 + 0.25f * a3) + wi1 * (0.75f * b2 + 0.25f * b3);
      t[pp][cl4 + 0] = (float)g[0] + h0;
      t[pp][cl4 + 1] = (float)g[1] + h1;
      t[pp][cl4 + 2] = (float)g[2] + h2;
      t[pp][cl4 + 3] = (float)g[3] + h3;
    }
    __syncthreads();
    float* ob = out + (long)b * 8388608 + (long)c0 * 16384 + p0;
    #pragma unroll
    for (int it = 0; it < 4; it++) {
      int cc = wv * 16 + it * 4 + hi;
      f32x4 v;
      v.x = t[l15b * 4 + 0][cc]; v.y = t[l15b * 4 + 1][cc];
      v.z = t[l15b * 4 + 2][cc]; v.w = t[l15b * 4 + 3][cc];
      *(f32x4*)(ob + (long)cc * 16384 + l15b * 4) = v;
    }
    __syncthreads();   // t WAR before next xx
  }
}

// ---------------------------------------------------------------------------
extern "C" void kernel_launch(void* const* d_in, const int* in_sizes, int n_in,
                              void* d_out, int out_size, void* d_ws, size_t ws_size,
                              hipStream_t stream)
{
  const float* x     = (const float*)d_in[0];
  const float* Wqkv  = (const float*)d_in[1];
  const float* bqkv  = (const float*)d_in[2];
  const float* Wproj = (const float*)d_in[3];
  const float* bproj = (const float*)d_in[4];
  float* out = (float*)d_out;

  char* w = (char*)d_ws;
  __bf16* WqkvT  = (__bf16*)w;  w += (size_t)1536 * 512 * 2;
  __bf16* WprojT = (__bf16*)w;  w += (size_t)512 * 512 * 2;
  __bf16* Xbf    = (__bf16*)w;  w += (size_t)65536 * 512 * 2;   // aliased as G
  __bf16* G      = Xbf;
  __bf16* P      = (__bf16*)w;  w += (size_t)2048 * 4096 * 2;

  bool batched = ws_size >= ((size_t)356 << 20);
  size_t mchunk = batched ? 65536 : 16384;
  __bf16* QKVbuf = (__bf16*)w;  w += mchunk * 1536 * 2;
  __bf16* Obuf   = (__bf16*)w;

  transpose_f32_bf16<<<dim3(24, 8), 256, 0, stream>>>(Wqkv, WqkvT, 512, 1536);
  transpose_f32_bf16<<<dim3(8, 8), 256, 0, stream>>>(Wproj, WprojT, 512, 512);
  convpool<<<8192, 256, 0, stream>>>(x, Xbf, P);

  int nch = batched ? 1 : 4;
  int mrows = (int)mchunk;
  for (int c = 0; c < nch; c++) {
    const __bf16* Ac = Xbf + (size_t)c * 16384 * 512;
    gemm256<<<(mrows / 256) * 6, 1024, 0, stream>>>(Ac, WqkvT, bqkv, QKVbuf, 1536, 6);
    attn4<<<(mrows / 4) * 32 / 256, 256, 0, stream>>>(
        QKVbuf, Obuf, mrows / 4, 64, 128, 4096, 16384);
    gemm256<<<(mrows / 256) * 2, 1024, 0, stream>>>(
        Obuf, WprojT, bproj, G + (size_t)c * 16384 * 512, 512, 2);
  }

  // local path
  gemm256<<<(16384 / 256) * 6, 1024, 0, stream>>>(P, WqkvT, bqkv, QKVbuf, 1536, 6);
  attn4<<<512, 256, 0, stream>>>(QKVbuf, Obuf, 4096, 32, 64, 1024, 4096);

  // fused stencil + upsample + add + transpose (Ol/stencil staged once per yy)
  final_v6<<<dim3(256, 4), 256, 0, stream>>>(G, Obuf, out);
}

// Round 27
// 437.071 us; speedup vs baseline: 1.3530x; 1.3530x over previous
//
#include <hip/hip_runtime.h>

typedef float f32x4 __attribute__((ext_vector_type(4)));
typedef float f32x2 __attribute__((ext_vector_type(2)));
typedef __bf16 bf16x8 __attribute__((ext_vector_type(8)));
typedef __bf16 bf16x4 __attribute__((ext_vector_type(4)));

__device__ __forceinline__ void gll16(const void* g, void* l) {
  __builtin_amdgcn_global_load_lds(
      (const __attribute__((address_space(1))) uint32_t*)g,
      (__attribute__((address_space(3))) uint32_t*)l, 16, 0, 0);
}

// ---------------------------------------------------------------------------
// GEMM 256x256 tile (measured-best config, R16/R19/R21/R25: ~151-154us QKV):
// C = A[Mx512]@B[512xN]+bias. BK=64, 8 waves (2M x 4N), per-wave 128x64.
// Plain-__syncthreads dbuf: stage(t+1) before compute(t); ~2500cy compute
// phase >> ~900cy HBM latency -> barrier drains a landed prefetch.
// XOR chunk swizzle (chunk ^= row&7) 0-conflict; XCD-chunked remap;
// swapped-mfma epilogue with direct bf16x4 stores.
// ---------------------------------------------------------------------------
__global__ __launch_bounds__(512, 2) void gemm256(
    const __bf16* __restrict__ A, const __bf16* __restrict__ BT,
    const float* __restrict__ bias, __bf16* __restrict__ C, int N, int gx)
{
  __shared__ __bf16 As[2][16384];   // 2 x 256x64 (32 KB each)
  __shared__ __bf16 Bs[2][16384];   // total 128 KB
  const int tid = threadIdx.x;       // 0..511
  const int wave = tid >> 6, lane = tid & 63;
  const int wr = (wave >> 2) * 128;  // 0 or 128
  const int wc = (wave & 3) * 64;    // 0,64,128,192
  const int l15 = lane & 15, l4 = lane >> 4;

  // XCD-chunked bijective remap (gridDim.x % 8 == 0)
  int lin = blockIdx.x;
  int olin = (lin & 7) * ((int)gridDim.x >> 3) + (lin >> 3);
  int bn = olin % gx, bm = olin / gx;
  const long arow0 = (long)bm * 256;
  const long brow0 = (long)bn * 256;

  const int srow = tid >> 3;         // 0..63
  const int sgc = ((tid & 7) ^ (srow & 7)) * 8;   // inverse-swizzled global chunk

  f32x4 acc[8][4] = {};

  auto stage = [&](int p, int kt) {
    #pragma unroll
    for (int s = 0; s < 4; s++) {
      int row = srow + s * 64;       // row&7 == srow&7
      gll16(A  + (arow0 + row) * 512 + kt + sgc, (char*)As[p] + s * 8192 + tid * 16);
      gll16(BT + (brow0 + row) * 512 + kt + sgc, (char*)Bs[p] + s * 8192 + tid * 16);
    }
  };

  stage(0, 0);
  __syncthreads();                  // drain prologue stage

  for (int t = 0; t < 8; t++) {
    int cur = t & 1;
    if (t < 7) stage(cur ^ 1, (t + 1) * 64);   // prefetch next K-tile (overlaps compute)
    #pragma unroll
    for (int kk = 0; kk < 2; kk++) {
      bf16x8 af[8], bfr[4];
      #pragma unroll
      for (int m = 0; m < 8; m++) {
        int row = wr + m * 16 + l15;
        int cp = ((kk * 4 + l4) ^ (row & 7)) * 8;
        af[m] = *(const bf16x8*)&As[cur][row * 64 + cp];
      }
      #pragma unroll
      for (int n = 0; n < 4; n++) {
        int row = wc + n * 16 + l15;
        int cp = ((kk * 4 + l4) ^ (row & 7)) * 8;
        bfr[n] = *(const bf16x8*)&Bs[cur][row * 64 + cp];
      }
      // swapped operands: lane holds C[row = wr+m*16+l15][col = wc+n*16+l4*4+k]
      #pragma unroll
      for (int m = 0; m < 8; m++)
        #pragma unroll
        for (int n = 0; n < 4; n++)
          acc[m][n] = __builtin_amdgcn_mfma_f32_16x16x32_bf16(bfr[n], af[m], acc[m][n], 0, 0, 0);
    }
    if (t < 7) __syncthreads();     // drains landed prefetch + WAR hazard
  }

  // epilogue: direct bf16x4 stores (4 consecutive cols per lane)
  #pragma unroll
  for (int m = 0; m < 8; m++) {
    long row = arow0 + wr + m * 16 + l15;
    __bf16* crow = C + row * (long)N + brow0;
    #pragma unroll
    for (int n = 0; n < 4; n++) {
      f32x4 bv = *(const f32x4*)(bias + brow0 + wc + n * 16 + l4 * 4);
      bf16x4 o;
      #pragma unroll
      for (int k = 0; k < 4; k++) o[k] = (__bf16)(acc[m][n][k] + bv[k]);
      *(bf16x4*)(crow + wc + n * 16 + l4 * 4) = o;
    }
  }
}

// ---------------------------------------------------------------------------
// Window attention v3: 2x2 windows, 8 heads, hd=64.
// 4 threads per (window, head) -- one per query token; full 128B rows
// consumed back-to-back; group-of-4 lanes share K/V addresses (L1 broadcast).
// ---------------------------------------------------------------------------
__global__ __launch_bounds__(256) void attn4(
    const __bf16* __restrict__ qkv, __bf16* __restrict__ o,
    int nwin, int wg, int Wimg, int wpb, int bst)
{
  int tid = blockIdx.x * 256 + threadIdx.x;
  int m = tid & 3;
  int head = (tid >> 2) & 7;
  int win = tid >> 5;
  if (win >= nwin) return;
  int b = win / wpb, wrm = win % wpb;
  int i = wrm / wg, j = wrm % wg;
  int t0 = b * bst + 2 * i * Wimg + 2 * j;
  int tn[4] = { t0, t0 + 1, t0 + Wimg, t0 + Wimg + 1 };
  int trow = tn[m];
  const int co = head * 64;

  float qf[64];
  #pragma unroll
  for (int c = 0; c < 8; c++) {
    bf16x8 v = *(const bf16x8*)(qkv + (long)trow * 1536 + co + c * 8);
    #pragma unroll
    for (int e = 0; e < 8; e++) qf[c * 8 + e] = (float)v[e];
  }

  float s[4];
  #pragma unroll
  for (int n = 0; n < 4; n++) {
    float acc = 0.f;
    #pragma unroll
    for (int c = 0; c < 8; c++) {
      bf16x8 kv = *(const bf16x8*)(qkv + (long)tn[n] * 1536 + 512 + co + c * 8);
      #pragma unroll
      for (int e = 0; e < 8; e++) acc += qf[c * 8 + e] * (float)kv[e];
    }
    s[n] = acc * 0.125f;
  }

  float mx = fmaxf(fmaxf(s[0], s[1]), fmaxf(s[2], s[3]));
  float e0 = __expf(s[0] - mx), e1 = __expf(s[1] - mx),
        e2 = __expf(s[2] - mx), e3 = __expf(s[3] - mx);
  float inv = 1.f / (e0 + e1 + e2 + e3);
  float w4[4] = { e0 * inv, e1 * inv, e2 * inv, e3 * inv };

  float of[64] = {};
  #pragma unroll
  for (int n = 0; n < 4; n++) {
    float wn = w4[n];
    #pragma unroll
    for (int c = 0; c < 8; c++) {
      bf16x8 vv = *(const bf16x8*)(qkv + (long)tn[n] * 1536 + 1024 + co + c * 8);
      #pragma unroll
      for (int e = 0; e < 8; e++) of[c * 8 + e] += wn * (float)vv[e];
    }
  }

  #pragma unroll
  for (int c = 0; c < 8; c++) {
    bf16x8 ov;
    #pragma unroll
    for (int e = 0; e < 8; e++) ov[e] = (__bf16)of[c * 8 + e];
    *(bf16x8*)(o + (long)trow * 512 + co + c * 8) = ov;
  }
}

// Transpose + fp32->bf16: out[N][K] = (bf16) in[K][N]
__global__ __launch_bounds__(256) void transpose_f32_bf16(
    const float* __restrict__ in, __bf16* __restrict__ out, int K, int N)
{
  __shared__ float t[64][65];
  int n0 = blockIdx.x * 64, k0 = blockIdx.y * 64;
  int tid = threadIdx.x;
  int nl4 = (tid & 15) * 4, kl = tid >> 4;
  #pragma unroll
  for (int p = 0; p < 4; p++) {
    int kk = kl + p * 16;
    f32x4 v = *(const f32x4*)(in + (long)(k0 + kk) * N + n0 + nl4);
    t[kk][nl4 + 0] = v.x; t[kk][nl4 + 1] = v.y; t[kk][nl4 + 2] = v.z; t[kk][nl4 + 3] = v.w;
  }
  __syncthreads();
  int ks = tid & 63, wv = tid >> 6;
  #pragma unroll
  for (int p = 0; p < 16; p++) {
    int nn = wv * 16 + p;
    out[(long)(n0 + nn) * K + k0 + ks] = (__bf16)t[ks][nn];
  }
}

// Fused: Xbf = bf16(x) (flat) AND P = AvgPool2d(2) of x viewed (B,C,128,128).
__global__ __launch_bounds__(256) void convpool(const float* __restrict__ x,
    __bf16* __restrict__ Xbf, __bf16* __restrict__ P)
{
  int t = blockIdx.x * 256 + threadIdx.x;   // 2,097,152 threads
  int j8 = (t & 15) * 8;
  int i2 = (t >> 4) & 63;
  long bc = t >> 10;
  const float* r0 = x + bc * 16384 + (2 * i2) * 128 + j8;
  f32x4 a0 = *(const f32x4*)r0,         a1 = *(const f32x4*)(r0 + 4);
  f32x4 b0 = *(const f32x4*)(r0 + 128), b1 = *(const f32x4*)(r0 + 132);
  bf16x8 xa, xb;
  xa[0] = (__bf16)a0.x; xa[1] = (__bf16)a0.y; xa[2] = (__bf16)a0.z; xa[3] = (__bf16)a0.w;
  xa[4] = (__bf16)a1.x; xa[5] = (__bf16)a1.y; xa[6] = (__bf16)a1.z; xa[7] = (__bf16)a1.w;
  xb[0] = (__bf16)b0.x; xb[1] = (__bf16)b0.y; xb[2] = (__bf16)b0.z; xb[3] = (__bf16)b0.w;
  xb[4] = (__bf16)b1.x; xb[5] = (__bf16)b1.y; xb[6] = (__bf16)b1.z; xb[7] = (__bf16)b1.w;
  *(bf16x8*)(Xbf + bc * 16384 + (2 * i2) * 128 + j8) = xa;
  *(bf16x8*)(Xbf + bc * 16384 + (2 * i2) * 128 + 128 + j8) = xb;
  bf16x4 p;
  p[0] = (__bf16)((a0.x + a0.y + b0.x + b0.y) * 0.25f);
  p[1] = (__bf16)((a0.z + a0.w + b0.z + b0.w) * 0.25f);
  p[2] = (__bf16)((a1.x + a1.y + b1.x + b1.y) * 0.25f);
  p[3] = (__bf16)((a1.z + a1.w + b1.z + b1.w) * 0.25f);
  *(bf16x4*)(P + bc * 4096 + i2 * 64 + (t & 15) * 4) = p;
}

// ---------------------------------------------------------------------------
// final_v6: one block per (yy, b) stages Ol + stencil ONCE, then loops over
// all 8 c-tiles (xx). Ol traffic /8, stencil /8, per-block work x8.
// LDS: t[64][65] overlays dead lbuf; 49.4KB -> 3 blocks/CU.
// ---------------------------------------------------------------------------
__global__ __launch_bounds__(256) void final_v6(
    const __bf16* __restrict__ G, const __bf16* __restrict__ Ol, float* __restrict__ out)
{
  __shared__ float smem[12352];                 // 49408 B
  float (*t)[65] = (float(*)[65])smem;          // [0, 16640)
  float* Sl = smem + 4160;                      // [16640, 49408): 8192 floats
  __bf16* lbuf = (__bf16*)smem;                 // [0, 16384): 8192 bf16

  int yy = blockIdx.x;             // 0..255 : p-tile / S-pair index
  int b  = blockIdx.y;
  int p0 = yy * 64;
  int tid = threadIdx.x;

  // phase 1: stage the block's two O_l channels (raw-reshape view)
  {
    const __bf16* src = Ol + ((long)b * 512 + (long)yy * 2) * 4096;
    #pragma unroll
    for (int i = 0; i < 4; i++)
      *(bf16x8*)&lbuf[i * 2048 + tid * 8] = *(const bf16x8*)(src + i * 2048 + tid * 8);
  }
  __syncthreads();

  // phase 2: stencil -> Sl (reflect pad baked in)
  #pragma unroll
  for (int kq = 0; kq < 32; kq++) {
    int s = tid + kq * 256;
    int j = s & 63, i = (s >> 6) & 63, lc = s >> 12;
    const __bf16* base = lbuf + lc * 4096;
    int im1 = (i == 0) ? 1 : i - 1;
    int jp1 = (j == 63) ? 62 : j + 1;
    Sl[s] = 0.5f * (float)base[im1 * 64 + j] + (float)base[i * 64 + j]
          + 0.5f * (float)base[i * 64 + jp1];
  }
  __syncthreads();   // lbuf dead from here; t overlays it

  int cl4 = (tid & 15) * 4, pl = tid >> 4;
  int l15b = tid & 15, hi = (tid >> 4) & 3, wv = tid >> 6;

  for (int xx = 0; xx < 8; xx++) {
    int c0 = xx * 64;
    const __bf16* Gb = G + ((long)b * 16384 + p0) * 512 + c0;
    #pragma unroll
    for (int q2 = 0; q2 < 4; q2++) {
      int pp = pl + q2 * 16;
      bf16x4 g = *(const bf16x4*)(Gb + (long)pp * 512 + cl4);
      int q = (p0 + pp) * 512 + c0 + cl4;            // quad-aligned
      int lc = (q >> 14) & 1;
      int rr = q & 16383, hh = rr >> 7, ww0 = rr & 127;
      const float* sb = Sl + lc * 4096;
      int i0, i1; float wi0, wi1;
      if (hh & 1) { i0 = hh >> 1; i1 = (i0 < 63) ? i0 + 1 : 63; wi0 = 0.75f; wi1 = 0.25f; }
      else        { i1 = hh >> 1; i0 = (i1 > 0) ? i1 - 1 : 0;   wi0 = 0.25f; wi1 = 0.75f; }
      int kc = ww0 >> 1;
      int cm1 = (kc > 0) ? kc - 1 : 0;
      int cp2 = (kc < 62) ? kc + 2 : 63;
      const float* r0p = sb + i0 * 64;
      const float* r1p = sb + i1 * 64;
      float a0 = r0p[cm1], a1 = r0p[kc], a2 = r0p[kc + 1], a3 = r0p[cp2];
      float b0 = r1p[cm1], b1 = r1p[kc], b2 = r1p[kc + 1], b3 = r1p[cp2];
      float h0 = wi0 * (0.25f * a0 + 0.75f * a1) + wi1 * (0.25f * b0 + 0.75f * b1);
      float h1 = wi0 * (0.75f * a1 + 0.25f * a2) + wi1 * (0.75f * b1 + 0.25f * b2);
      float h2 = wi0 * (0.25f * a1 + 0.75f * a2) + wi1 * (0.25f * b1 + 0.75f * b2);
      float h3 = wi0 * (0.75f * a2 + 0.25f * a3) + wi1 * (0.75f * b2 + 0.25f * b3);
      t[pp][cl4 + 0] = (float)g[0] + h0;
      t[pp][cl4 + 1] = (float)g[1] + h1;
      t[pp][cl4 + 2] = (float)g[2] + h2;
      t[pp][cl4 + 3] = (float)g[3] + h3;
    }
    __syncthreads();
    float* ob = out + (long)b * 8388608 + (long)c0 * 16384 + p0;
    #pragma unroll
    for (int it = 0; it < 4; it++) {
      int cc = wv * 16 + it * 4 + hi;
      f32x4 v;
      v.x = t[l15b * 4 + 0][cc]; v.y = t[l15b * 4 + 1][cc];
      v.z = t[l15b * 4 + 2][cc]; v.w = t[l15b * 4 + 3][cc];
      *(f32x4*)(ob + (long)cc * 16384 + l15b * 4) = v;
    }
    __syncthreads();   // t WAR before next xx
  }
}

// ---------------------------------------------------------------------------
extern "C" void kernel_launch(void* const* d_in, const int* in_sizes, int n_in,
                              void* d_out, int out_size, void* d_ws, size_t ws_size,
                              hipStream_t stream)
{
  const float* x     = (const float*)d_in[0];
  const float* Wqkv  = (const float*)d_in[1];
  const float* bqkv  = (const float*)d_in[2];
  const float* Wproj = (const float*)d_in[3];
  const float* bproj = (const float*)d_in[4];
  float* out = (float*)d_out;

  char* w = (char*)d_ws;
  __bf16* WqkvT  = (__bf16*)w;  w += (size_t)1536 * 512 * 2;
  __bf16* WprojT = (__bf16*)w;  w += (size_t)512 * 512 * 2;
  __bf16* Xbf    = (__bf16*)w;  w += (size_t)65536 * 512 * 2;   // aliased as G
  __bf16* G      = Xbf;
  __bf16* P      = (__bf16*)w;  w += (size_t)2048 * 4096 * 2;

  bool batched = ws_size >= ((size_t)356 << 20);
  size_t mchunk = batched ? 65536 : 16384;
  __bf16* QKVbuf = (__bf16*)w;  w += mchunk * 1536 * 2;
  __bf16* Obuf   = (__bf16*)w;

  transpose_f32_bf16<<<dim3(24, 8), 256, 0, stream>>>(Wqkv, WqkvT, 512, 1536);
  transpose_f32_bf16<<<dim3(8, 8), 256, 0, stream>>>(Wproj, WprojT, 512, 512);
  convpool<<<8192, 256, 0, stream>>>(x, Xbf, P);

  int nch = batched ? 1 : 4;
  int mrows = (int)mchunk;
  for (int c = 0; c < nch; c++) {
    const __bf16* Ac = Xbf + (size_t)c * 16384 * 512;
    gemm256<<<(mrows / 256) * 6, 512, 0, stream>>>(Ac, WqkvT, bqkv, QKVbuf, 1536, 6);
    attn4<<<(mrows / 4) * 32 / 256, 256, 0, stream>>>(
        QKVbuf, Obuf, mrows / 4, 64, 128, 4096, 16384);
    gemm256<<<(mrows / 256) * 2, 512, 0, stream>>>(
        Obuf, WprojT, bproj, G + (size_t)c * 16384 * 512, 512, 2);
  }

  // local path
  gemm256<<<(16384 / 256) * 6, 512, 0, stream>>>(P, WqkvT, bqkv, QKVbuf, 1536, 6);
  attn4<<<512, 256, 0, stream>>>(QKVbuf, Obuf, 4096, 32, 64, 1024, 4096);

  // fused stencil + upsample + add + transpose (Ol/stencil staged once per yy)
  final_v6<<<dim3(256, 4), 256, 0, stream>>>(G, Obuf, out);
}